// Round 2
// baseline (664.031 us; speedup 1.0000x reference)
//
#include <hip/hip_runtime.h>

// irreps Linear: out[n, off_l + w*d + i] = 0.125 * sum_u x[n, off_l + u*d + i] * Wl[u][w]
// N=262144 rows of 576 = [64x(d=1) | 64x(d=3) | 64x(d=5)].
// Memory-bound: 1.21 GB @ ~6.3 TB/s => ~192 us floor.
// R2: occupancy was the binding constraint (22.7%, 2 blocks/CU due to 61KB LDS).
//  - weights now live in 24 VGPRs/wave (each wave uses exactly one wt column-tile),
//    loaded from global (L2-hot); LDS = x-tile only (36 KB) -> 4 blocks/CU.
//  - single kernel, nontemporal stores.

typedef _Float16 half4  __attribute__((ext_vector_type(4)));
typedef float    f32x4  __attribute__((ext_vector_type(4)));
typedef float    fltx4  __attribute__((ext_vector_type(4)));

#define RPB     32                  // rows per block
#define NROWS   262144
#define XROWS   288                 // 32*1 + 32*3 + 32*5 rows of 64 f16 (128 B each)
#define LDS_BYTES (XROWS * 128)     // 36864 -> 4 blocks/CU

// stage one l-segment of the x tile into LDS as f16, rows = (n_local*D + i), cols = u
// XOR swizzle (row&7)<<4 breaks the 128B-stride same-bank pattern (G4).
template<int D, int OFF, int SEGROW, int F4PR>
__device__ __forceinline__ void stage_seg(unsigned char* lds, const float* __restrict__ xrow0, int tid) {
#pragma unroll
  for (int it = 0; it < (RPB * F4PR + 255) / 256; ++it) {
    int t = tid + it * 256;
    if (RPB * F4PR % 256 != 0 && t >= RPB * F4PR) break;
    int row = t / F4PR;                 // const divisor -> magic mul
    int f4  = t - row * F4PR;
    fltx4 v = *(const fltx4*)(xrow0 + (long long)row * 576 + OFF + f4 * 4);
    int idx = f4 * 4;                   // element index within segment (= u*D + i)
    if (D == 1) {
      // 4 consecutive u, same LDS row: one 8-byte write (swizzle preserves 8B chunks)
      int lrow = SEGROW + row;
      int b = (lrow * 128 + idx * 2) ^ ((lrow & 7) << 4);
      half4 h = { (_Float16)v[0], (_Float16)v[1], (_Float16)v[2], (_Float16)v[3] };
      *(half4*)(lds + b) = h;
    } else {
#pragma unroll
      for (int j = 0; j < 4; ++j) {
        int u = (idx + j) / D;          // const divisor
        int i = (idx + j) - u * D;
        int lrow = SEGROW + row * D + i;
        int b = (lrow * 128 + u * 2) ^ ((lrow & 7) << 4);
        *(_Float16*)(lds + b) = (_Float16)v[j];
      }
    }
  }
}

// B-fragments for this wave's wt: bf[s][j] = W[u = s*16 + 4*laneq + j][w = wt*16 + lane15]
__device__ __forceinline__ void load_bfrag(const float* __restrict__ W, int wt,
                                           int lane15, int laneq, half4 bf[4]) {
  int w = wt * 16 + lane15;
#pragma unroll
  for (int s = 0; s < 4; ++s) {
    int u0 = s * 16 + laneq * 4;
#pragma unroll
    for (int j = 0; j < 4; ++j)
      bf[s][j] = (_Float16)W[(u0 + j) * 64 + w];   // 16-lane groups read 64B contig
  }
}

// all m-tiles of one l-segment for this wave's wt
template<int D, int OFF, int SEGROW, int MT>
__device__ __forceinline__ void compute_seg(const unsigned char* lds, float* __restrict__ out,
                                            long long n0, int wt, int lane15, int laneq,
                                            const half4 bf[4]) {
  const int coff = laneq * 8;           // k-chunk byte offset within a row
  const int w = wt * 16 + lane15;
#pragma unroll
  for (int mt = 0; mt < MT; ++mt) {
    int arow  = SEGROW + mt * 16 + lane15;   // A: m = lane%16, k = s*16 + 4*laneq + j
    int abase = arow * 128;
    int aswz  = (arow & 7) << 4;
    f32x4 acc = {0.f, 0.f, 0.f, 0.f};
#pragma unroll
    for (int s = 0; s < 4; ++s) {
      half4 a = *(const half4*)(lds + abase + ((s * 32 + coff) ^ aswz));
      acc = __builtin_amdgcn_mfma_f32_16x16x16f16(a, bf[s], acc, 0, 0, 0);
    }
    // D-frag: col = lane&15 (w), row = 4*(lane>>4) + j  [HW-verified mapping]
    int r0 = mt * 16 + laneq * 4;
#pragma unroll
    for (int j = 0; j < 4; ++j) {
      int r = r0 + j;
      int n = r / D;                    // const divisor
      int i = r - n * D;
      __builtin_nontemporal_store(0.125f * acc[j],
                                  out + (n0 + n) * 576 + OFF + w * D + i);
    }
  }
}

__global__ __launch_bounds__(256, 4) void linear_irreps(
    const float* __restrict__ x,
    const float* __restrict__ w0, const float* __restrict__ w1, const float* __restrict__ w2,
    float* __restrict__ out) {
  __shared__ __align__(16) unsigned char lds[LDS_BYTES];
  const int tid = threadIdx.x;
  const int lane = tid & 63, wave = tid >> 6;
  const int lane15 = lane & 15, laneq = lane >> 4;
  const int wt = wave;                  // 4 waves <-> 4 w-tiles (w = wt*16 .. +15)
  const long long base = (long long)blockIdx.x * (RPB * 576);

  // weights -> registers first (independent of x; latency overlaps staging)
  half4 bf0[4], bf1[4], bf2[4];
  load_bfrag(w0, wt, lane15, laneq, bf0);
  load_bfrag(w1, wt, lane15, laneq, bf1);
  load_bfrag(w2, wt, lane15, laneq, bf2);

  // stage x tile: contiguous 72KB global span -> f16 LDS, transposed to [row(n,i)][u]
  stage_seg<1,   0,   0, 16>(lds, x + base, tid);
  stage_seg<3,  64,  32, 48>(lds, x + base, tid);
  stage_seg<5, 256, 128, 80>(lds, x + base, tid);
  __syncthreads();

  const long long n0 = (long long)blockIdx.x * RPB;
  compute_seg<1,   0,   0,  2>(lds, out, n0, wt, lane15, laneq, bf0);
  compute_seg<3,  64,  32,  6>(lds, out, n0, wt, lane15, laneq, bf1);
  compute_seg<5, 256, 128, 10>(lds, out, n0, wt, lane15, laneq, bf2);
}

extern "C" void kernel_launch(void* const* d_in, const int* in_sizes, int n_in,
                              void* d_out, int out_size, void* d_ws, size_t ws_size,
                              hipStream_t stream) {
  const float* x  = (const float*)d_in[0];
  const float* w0 = (const float*)d_in[1];
  const float* w1 = (const float*)d_in[2];
  const float* w2 = (const float*)d_in[3];
  float* out = (float*)d_out;
  linear_irreps<<<NROWS / RPB, 256, 0, stream>>>(x, w0, w1, w2, out);
}

// Round 3
// 248.373 us; speedup vs baseline: 2.6735x; 2.6735x over previous
//
#include <hip/hip_runtime.h>

// irreps Linear: out[n, off_l + w*d + i] = 0.125 * sum_u x[n, off_l + u*d + i] * Wl[u][w]
// N=262144 rows of 576 = [64x(d=1) | 64x(d=3) | 64x(d=5)].
// BW floor: 1.21 GB @ ~6.3 TB/s => ~192 us.
// R3 theory: R1/R2 were capped by L2 write-TRANSACTION rate (36 scalar dword
// stores/thread = 151M 4B transactions), not bytes. Fix: stage f32 outputs in
// LDS, then copy out as fully-coalesced dwordx4 (38M 16B transactions).
//  - RPB=16 so the out tile (16x576 f32 = 36864 B) exactly reuses the LDS buffer.
//  - weights stay in VGPRs (24/wave); LDS 36 KB -> 4 blocks/CU.
//  - NO nontemporal stores (R2 lesson: nt scalar stores inflated HBM writes 2.5x).

typedef _Float16 half4  __attribute__((ext_vector_type(4)));
typedef float    f32x4  __attribute__((ext_vector_type(4)));

#define RPB      16                 // rows per block
#define NROWS    262144
#define ROWF     576                // floats per row
#define XROWS    (RPB * 9)          // 144 LDS rows (16*1 + 16*3 + 16*5) of 128 B
#define OUTBYTES (RPB * ROWF * 4)   // 36864 = out tile f32
#define LDS_BYTES OUTBYTES          // x-stage (18432 B) reuses the same buffer

// ---- stage one l-segment of x into LDS as f16; LDS rows = (n_local*D + i), cols = u.
// XOR swizzle (row&7)<<4 breaks the 128B-stride same-bank pattern.
template<int D, int OFF, int SEGROW, int F4PR>   // F4PR = float4s per 576-f row in this seg
__device__ __forceinline__ void stage_seg(unsigned char* lds, const float* __restrict__ xrow0, int tid) {
#pragma unroll
  for (int it = 0; it < RPB * F4PR / 256; ++it) {  // 1 / 3 / 5 iters, no tail
    int t = tid + it * 256;
    int row = t / F4PR;                 // const divisor -> magic mul
    int f4  = t - row * F4PR;
    f32x4 v = *(const f32x4*)(xrow0 + (long long)row * ROWF + OFF + f4 * 4);
    int idx = f4 * 4;                   // element index within segment (= u*D + i)
    if (D == 1) {
      int lrow = SEGROW + row;
      int b = (lrow * 128 + idx * 2) ^ ((lrow & 7) << 4);
      half4 h = { (_Float16)v[0], (_Float16)v[1], (_Float16)v[2], (_Float16)v[3] };
      *(half4*)(lds + b) = h;           // 4 consecutive u: one 8B write
    } else {
#pragma unroll
      for (int j = 0; j < 4; ++j) {
        int u = (idx + j) / D;          // const divisor
        int i = (idx + j) - u * D;
        int lrow = SEGROW + row * D + i;
        int b = (lrow * 128 + u * 2) ^ ((lrow & 7) << 4);
        *(_Float16*)(lds + b) = (_Float16)v[j];
      }
    }
  }
}

// B-fragments for this wave's wt: bf[s][j] = W[u = s*16 + 4*laneq + j][w = wt*16 + lane15]
__device__ __forceinline__ void load_bfrag(const float* __restrict__ W, int wt,
                                           int lane15, int laneq, half4 bf[4]) {
  int w = wt * 16 + lane15;
#pragma unroll
  for (int s = 0; s < 4; ++s) {
    int u0 = s * 16 + laneq * 4;
#pragma unroll
    for (int j = 0; j < 4; ++j)
      bf[s][j] = (_Float16)W[(u0 + j) * 64 + w];   // 16-lane groups read 64B contig
  }
}

// MFMA all m-tiles of one l-segment for this wave's w-tile
template<int SEGROW, int MT>
__device__ __forceinline__ void compute_seg(const unsigned char* lds, int lane15, int laneq,
                                            const half4 bf[4], f32x4 acc[MT]) {
  const int coff = laneq * 8;           // k-chunk byte offset within a row
#pragma unroll
  for (int mt = 0; mt < MT; ++mt) {
    int arow  = SEGROW + mt * 16 + lane15;   // A: m = lane%16, k = s*16 + 4*laneq + j
    int abase = arow * 128;
    int aswz  = (arow & 7) << 4;
    acc[mt] = (f32x4){0.f, 0.f, 0.f, 0.f};
#pragma unroll
    for (int s = 0; s < 4; ++s) {
      half4 a = *(const half4*)(lds + abase + ((s * 32 + coff) ^ aswz));
      acc[mt] = __builtin_amdgcn_mfma_f32_16x16x16f16(a, bf[s], acc[mt], 0, 0, 0);
    }
  }
}

// scatter acc fragments into the f32 out tile in LDS ([RPB][576] row-major)
template<int D, int OFF, int MT>
__device__ __forceinline__ void scatter_seg(unsigned char* lds, int wt, int lane15, int laneq,
                                            const f32x4 acc[MT]) {
  const int w = wt * 16 + lane15;
#pragma unroll
  for (int mt = 0; mt < MT; ++mt) {
#pragma unroll
    for (int j = 0; j < 4; ++j) {
      int r = mt * 16 + laneq * 4 + j;  // D-frag: col = lane&15, row = 4*laneq + j
      int n = r / D;                    // const divisor
      int i = r - n * D;
      *(float*)(lds + n * (ROWF * 4) + (OFF + w * D + i) * 4) = 0.125f * acc[mt][j];
    }
  }
}

__global__ __launch_bounds__(256, 4) void linear_irreps(
    const float* __restrict__ x,
    const float* __restrict__ w0, const float* __restrict__ w1, const float* __restrict__ w2,
    float* __restrict__ out) {
  __shared__ __align__(16) unsigned char lds[LDS_BYTES];
  const int tid = threadIdx.x;
  const int lane = tid & 63, wave = tid >> 6;
  const int lane15 = lane & 15, laneq = lane >> 4;
  const int wt = wave;                  // 4 waves <-> 4 w-tiles (w = wt*16 .. +15)
  const long long base = (long long)blockIdx.x * (RPB * ROWF);

  // weights -> registers (independent of x; latency overlaps staging)
  half4 bf0[4], bf1[4], bf2[4];
  load_bfrag(w0, wt, lane15, laneq, bf0);
  load_bfrag(w1, wt, lane15, laneq, bf1);
  load_bfrag(w2, wt, lane15, laneq, bf2);

  // stage x tile (36 KB contiguous global span -> f16 LDS, [row(n,i)][u])
  stage_seg<1,   0,   0, 16>(lds, x + base, tid);
  stage_seg<3,  64,  16, 48>(lds, x + base, tid);
  stage_seg<5, 256,  64, 80>(lds, x + base, tid);
  __syncthreads();

  // MFMA into registers (36 f32 accs/thread)
  f32x4 acc1[1], acc3[3], acc5[5];
  compute_seg<  0, 1>(lds, lane15, laneq, bf0, acc1);
  compute_seg< 16, 3>(lds, lane15, laneq, bf1, acc3);
  compute_seg< 64, 5>(lds, lane15, laneq, bf2, acc5);
  __syncthreads();                      // all A-reads done before overwriting LDS

  // scatter f32 results into LDS out tile
  scatter_seg<1,   0, 1>(lds, wt, lane15, laneq, acc1);
  scatter_seg<3,  64, 3>(lds, wt, lane15, laneq, acc3);
  scatter_seg<5, 256, 5>(lds, wt, lane15, laneq, acc5);
  __syncthreads();

  // fully-coalesced copy out: 9 x dwordx4 per thread (1 KB/wave-instruction)
#pragma unroll
  for (int k = 0; k < OUTBYTES / 4096; ++k) {      // 9
    int q = tid + k * 256;
    f32x4 v = *(const f32x4*)(lds + q * 16);
    *(f32x4*)(out + base + q * 4) = v;
  }
}

extern "C" void kernel_launch(void* const* d_in, const int* in_sizes, int n_in,
                              void* d_out, int out_size, void* d_ws, size_t ws_size,
                              hipStream_t stream) {
  const float* x  = (const float*)d_in[0];
  const float* w0 = (const float*)d_in[1];
  const float* w1 = (const float*)d_in[2];
  const float* w2 = (const float*)d_in[3];
  float* out = (float*)d_out;
  linear_irreps<<<NROWS / RPB, 256, 0, stream>>>(x, w0, w1, w2, out);
}